// Round 5
// baseline (487.914 us; speedup 1.0000x reference)
//
#include <hip/hip_runtime.h>
#include <hip/hip_bf16.h>
#include <hip/hip_fp16.h>

#define DIMK 1024
#define SEQ  2048
#define BATCH 4
#define NTOK (BATCH*SEQ)                    // 8192
#define PROJ_ELEMS ((size_t)NTOK*DIMK)      // 8388608
#define LD 2048                             // leading dim (elements) of every GEMM operand

typedef unsigned short ushort_t;
typedef __attribute__((ext_vector_type(8))) short short8;   // 8 x bf16 (4 VGPRs)
typedef __attribute__((ext_vector_type(4))) float float4v;  // MFMA accumulator

#define MFMA_BF16 __builtin_amdgcn_mfma_f32_16x16x32_bf16

__device__ __forceinline__ unsigned short f2bf(float f) {
    union { float f; unsigned int i; } x; x.f = f;
    unsigned int r = x.i + 0x7fffu + ((x.i >> 16) & 1u);    // RNE
    return (unsigned short)(r >> 16);
}

// global -> LDS direct copy, 16 B per lane. LDS dest is wave-uniform base;
// HW scatters lane i to base + i*16. Source address is per-lane.
__device__ __forceinline__ void gld_lds16(const void* g, void* l) {
    auto gp = reinterpret_cast<const __attribute__((address_space(1))) unsigned int*>(
        reinterpret_cast<uintptr_t>(g));
    auto lp = reinterpret_cast<__attribute__((address_space(3))) unsigned int*>(
        reinterpret_cast<uintptr_t>(l));
    __builtin_amdgcn_global_load_lds(gp, lp, 16, 0, 0);
}

// Stage one pair of 16x32 sub-chunk units (rg0, rg0+1): 2 global_load_lds per
// thread. Source swizzle (verified conflict-free + coalesced): within each
// 16-row unit, row g's 16B chunk c sits at slot (c + g/2) & 3 — a permutation
// inside each 64B line, so staging lanes 4g..4g+3 still cover one aligned
// 64B segment.
__device__ __forceinline__ void stage2(const ushort_t* __restrict__ gbase,
                                       ushort_t* lbase, int kcol,
                                       int rg0, int g, int scol)
{
    gld_lds16(gbase + (size_t)(rg0 * 16 + g) * LD + kcol + scol,
              lbase + rg0 * 512);
    gld_lds16(gbase + (size_t)(rg0 * 16 + 16 + g) * LD + kcol + scol,
              lbase + rg0 * 512 + 512);
}

// ---------------------------------------------------------------------------
// 256x256-tile MFMA core, DEPTH-3 pipeline + cross-half register read-ahead
// (R5). C(256x256) += A(256xK) * B(256xK)^T, row-major bf16, ld=2048.
// Block = 512 threads = 8 waves (2M x 4N); wave output = 128x64.
// K advances in 32-col HALVES H = 0..L-1 (L = kend/32, multiple of 8).
// LDS: 4 half-slots per operand (slot = H & 3), 4*8192 elem * 2 = 128 KiB.
//
// R4 post-mortem: per half, LDS window (96 KiB @ 85 B/cyc = 1156 cyc) and
// MFMA burst (64/SIMD * 18.5 = 1184 cyc) fully SERIALIZED (sum=2340 ≈
// measured 2275) because each half's reads feed the same half's MFMAs.
// Fix: read B + A-lo of half H+1 into a second register set DURING half H
// (their data is resident: staging runs 3 halves ahead), so those ds_reads
// retire under H's MFMAs. Only A-hi of H is read in-half (needed at MFMA #17,
// ~600 cyc in — returns in time). Full 12-frag dbuf would need 280 VGPRs and
// halve occupancy; this split needs ~208+temps and keeps 2 waves/SIMD.
//
// Per half H: { read A-hi(H); read B,A-lo(H+1); stage H+3; 32 MFMA;
//               vmcnt(4); barrier; rotate reg sets }
// vmcnt: outstanding at end of H = {H+2 (staged during H-1), H+3 (during H)}
//   = 8 -> vmcnt(4) drains H+2, which is exactly what the reads issued during
//   H+1 require. Tail: end of L-3 -> vmcnt(0) (drains L-1); L-2, L-1: none.
// Overwrite safety: stage during H targets slot (H+3)&3 == (H-1)&3; all
//   reads of H-1 retired before the end-of-(H-1) barrier (consumed by MFMA).
// Post-barrier compiler fences stop ds_reads hoisting above the barrier
//   (at depth 3 that hoist would be a real cross-wave race).
// ---------------------------------------------------------------------------
__device__ __forceinline__ void gemm_core256(
    const ushort_t* __restrict__ Arow,   // A + m0*LD  (m0 = 256-row tile base)
    const ushort_t* __restrict__ Brow,   // B + n0*LD
    int kend,                            // multiple of 256
    ushort_t* Alds, ushort_t* Blds,      // 32768 elements each (4 slots x 8192)
    float4v acc[8][4], int wid, int lane)
{
    const int g    = lane >> 2;                         // staging row in unit
    const int sx   = lane & 3;                          // staging slot in 64B line
    const int scol = ((sx - (g >> 1)) & 3) * 8;         // swizzled source chunk
    const int r16  = lane & 15;                         // fragment row
    const int quad = lane >> 4;                         // fragment k-chunk
    const int roff = r16 * 32 + ((quad + (r16 >> 1)) & 3) * 8;  // swizzled read
    const int wm8 = (wid >> 2) * 8;      // A unit base (0 or 8)
    const int wn4 = (wid & 3) * 4;       // B unit base
    const int rg0 = wid * 2;             // this wave's 2 staging units
    const int L = kend >> 5;             // number of 32-col halves (mult of 8)

    // stage half X -> slot X&3 (B first then A: 4 vm loads per STAGE)
    auto STAGE = [&](int X) {
        const int sl = (X & 3) * 8192;
        const int kc = X * 32;
        stage2(Brow, Blds + sl, kc, rg0, g, scol);
        stage2(Arow, Alds + sl, kc, rg0, g, scol);
    };

    short8 bc[4], alo[4], bn[4], aln[4], ahi[4];

#define READ_AHI(C)                                                         \
    _Pragma("unroll")                                                       \
    for (int i = 0; i < 4; ++i)                                             \
        ahi[i] = *(const short8*)(Alds + (C) * 8192 + (wm8 + 4 + i) * 512 + roff);

#define READ_NXT(N)                                                         \
    _Pragma("unroll")                                                       \
    for (int j = 0; j < 4; ++j)                                             \
        bn[j] = *(const short8*)(Blds + (N) * 8192 + (wn4 + j) * 512 + roff); \
    _Pragma("unroll")                                                       \
    for (int i = 0; i < 4; ++i)                                             \
        aln[i] = *(const short8*)(Alds + (N) * 8192 + (wm8 + i) * 512 + roff);

#define MFMA32()                                                            \
    __builtin_amdgcn_s_setprio(1);                                          \
    _Pragma("unroll")                                                       \
    for (int i = 0; i < 4; ++i)                                             \
        _Pragma("unroll")                                                   \
        for (int j = 0; j < 4; ++j)                                         \
            acc[i][j] = MFMA_BF16(alo[i], bc[j], acc[i][j], 0, 0, 0);       \
    _Pragma("unroll")                                                       \
    for (int i = 0; i < 4; ++i)                                             \
        _Pragma("unroll")                                                   \
        for (int j = 0; j < 4; ++j)                                         \
            acc[4 + i][j] = MFMA_BF16(ahi[i], bc[j], acc[4 + i][j], 0, 0, 0); \
    __builtin_amdgcn_s_setprio(0);

#define ROTATE()                                                            \
    _Pragma("unroll")                                                       \
    for (int q = 0; q < 4; ++q) { bc[q] = bn[q]; alo[q] = aln[q]; }

#define HALF_MAIN(C, N, Xst)                                                \
    READ_AHI(C)                                                             \
    READ_NXT(N)                                                             \
    STAGE(Xst);                                                             \
    MFMA32()                                                                \
    asm volatile("s_waitcnt vmcnt(4)" ::: "memory");                        \
    __builtin_amdgcn_s_barrier();                                           \
    asm volatile("" ::: "memory");                                          \
    ROTATE()

    // prologue: stage halves 0,1,2 (12 loads); drain to 4 -> halves 0,1
    // resident; pre-read half0's B + A-lo.
    STAGE(0); STAGE(1); STAGE(2);
    asm volatile("s_waitcnt vmcnt(4)" ::: "memory");
    __builtin_amdgcn_s_barrier();
    asm volatile("" ::: "memory");
    #pragma unroll
    for (int j = 0; j < 4; ++j)
        bc[j] = *(const short8*)(Blds + (wn4 + j) * 512 + roff);
    #pragma unroll
    for (int i = 0; i < 4; ++i)
        alo[i] = *(const short8*)(Alds + (wm8 + i) * 512 + roff);

    // main: halves 0 .. L-5 (groups of 4, slots 0,1,2,3)
    for (int H = 0; H + 7 < L; H += 4) {
        HALF_MAIN(0, 1, H + 3)
        HALF_MAIN(1, 2, H + 4)
        HALF_MAIN(2, 3, H + 5)
        HALF_MAIN(3, 0, H + 6)
    }

    // epilogue group: halves L-4 .. L-1 (slots 0,1,2,3)
    HALF_MAIN(0, 1, L - 1)              // X = L-4: last stage
    // X = L-3: no stage; drain everything (L-1's data needed next half)
    READ_AHI(1)
    READ_NXT(2)
    MFMA32()
    asm volatile("s_waitcnt vmcnt(0)" ::: "memory");
    __builtin_amdgcn_s_barrier();
    asm volatile("" ::: "memory");
    ROTATE()
    // X = L-2: no stage, nothing outstanding
    READ_AHI(2)
    READ_NXT(3)
    MFMA32()
    ROTATE()
    // X = L-1: final half
    READ_AHI(3)
    MFMA32()

#undef READ_AHI
#undef READ_NXT
#undef MFMA32
#undef ROTATE
#undef HALF_MAIN
}

// ---------------------------------------------------------------------------
// Merged projection GEMM: [Q|K|V]cat[8192,2048] = Zcat[8192,2048] @ Wall^T,
// Wall = [Wsq;Wsk;Wsv] rows 0..6143. grid (24, 32); n-tile picks the output.
// ---------------------------------------------------------------------------
__global__ __launch_bounds__(512, 2)
void gemm_proj(const ushort_t* __restrict__ A, const ushort_t* __restrict__ B,
               ushort_t* __restrict__ Cq, ushort_t* __restrict__ Ck,
               ushort_t* __restrict__ Cv)
{
    __shared__ ushort_t smem[65536];           // 128 KiB
    const int tid = threadIdx.x, wid = tid >> 6, lane = tid & 63;
    const int m0 = blockIdx.y * 256;
    const int n0g = blockIdx.x * 256;          // 0..5888
    ushort_t* C = (n0g < 2048) ? Cq : ((n0g < 4096) ? Ck : Cv);
    const int n0 = n0g & 2047;
    float4v acc[8][4] = {};
    gemm_core256(A + (size_t)m0 * LD, B + (size_t)n0g * LD, 2048,
                 smem, smem + 32768, acc, wid, lane);

    const int wm = wid >> 2, wn = wid & 3;
    const int col16 = lane & 15, quad = lane >> 4;
    #pragma unroll
    for (int i = 0; i < 8; ++i)
        #pragma unroll
        for (int j = 0; j < 4; ++j) {
            const int n = n0 + wn * 64 + j * 16 + col16;
            #pragma unroll
            for (int r = 0; r < 4; ++r) {
                const int m = m0 + wm * 128 + i * 16 + quad * 4 + r;
                C[(size_t)m * LD + n] = f2bf(acc[i][j][r]);
            }
        }
}

// ---------------------------------------------------------------------------
// Scores GEMM (causal tiles): S[b][s][t] fp16 = (Qcat@Kcat^T)*scale
// grid (8 t-tiles, 8 s-tiles, 4 batches); skip jt>it.
// ---------------------------------------------------------------------------
__global__ __launch_bounds__(512, 2)
void gemm_scores(const ushort_t* __restrict__ Q, const ushort_t* __restrict__ K,
                 __half* __restrict__ S)
{
    const int jt = blockIdx.x, it = blockIdx.y, b = blockIdx.z;
    if (jt > it) return;
    __shared__ ushort_t smem[65536];
    const int tid = threadIdx.x, wid = tid >> 6, lane = tid & 63;
    const size_t boff = (size_t)b * SEQ * LD;
    float4v acc[8][4] = {};
    gemm_core256(Q + boff + (size_t)it * 256 * LD, K + boff + (size_t)jt * 256 * LD,
                 2048, smem, smem + 32768, acc, wid, lane);

    const int wm = wid >> 2, wn = wid & 3;
    const int col16 = lane & 15, quad = lane >> 4;
    const float scale = 0.03125f;  // 1024^-0.5
    __half* Sb = S + (size_t)b * SEQ * SEQ;
    #pragma unroll
    for (int i = 0; i < 8; ++i)
        #pragma unroll
        for (int j = 0; j < 4; ++j) {
            const int t = jt * 256 + wn * 64 + j * 16 + col16;
            #pragma unroll
            for (int r = 0; r < 4; ++r) {
                const int s = it * 256 + wm * 128 + i * 16 + quad * 4 + r;
                Sb[(size_t)s * SEQ + t] = __float2half(acc[i][j][r] * scale);
            }
        }
}

// ---------------------------------------------------------------------------
// PV GEMM: out[{r,i}][b][s][d] fp32 = P[b] @ VTstack[b]^T, K extent causal
// (P rows are zero-padded to 256 multiples by the softmax kernel).
// grid (8 n-tiles, 8 s-tiles, 4 batches). n<1024 -> real, else imag.
// ---------------------------------------------------------------------------
__global__ __launch_bounds__(512, 2)
void gemm_pv(const ushort_t* __restrict__ P, const ushort_t* __restrict__ VT,
             float* __restrict__ out)
{
    const int nt = blockIdx.x, mt = blockIdx.y, b = blockIdx.z;
    __shared__ ushort_t smem[65536];
    const int tid = threadIdx.x, wid = tid >> 6, lane = tid & 63;
    const int kend = (mt + 1) * 256;
    float4v acc[8][4] = {};
    gemm_core256(P + (size_t)b * SEQ * SEQ + (size_t)mt * 256 * LD,
                 VT + (size_t)b * LD * LD + (size_t)nt * 256 * LD,
                 kend, smem, smem + 32768, acc, wid, lane);

    const int wm = wid >> 2, wn = wid & 3;
    const int col16 = lane & 15, quad = lane >> 4;
    #pragma unroll
    for (int i = 0; i < 8; ++i)
        #pragma unroll
        for (int j = 0; j < 4; ++j) {
            const int n = nt * 256 + wn * 64 + j * 16 + col16;
            float* dst = out + ((n < 1024) ? 0 : PROJ_ELEMS);
            const int d = n & 1023;
            #pragma unroll
            for (int r = 0; r < 4; ++r) {
                const int s = mt * 256 + wm * 128 + i * 16 + quad * 4 + r;
                dst[((size_t)b * SEQ + s) * DIMK + d] = acc[i][j][r];
            }
        }
}

// ---------------------------------------------------------------------------
// Input converts
// ---------------------------------------------------------------------------
__global__ __launch_bounds__(256)
void zcat_kernel(const float* __restrict__ zr, const float* __restrict__ zi,
                 ushort_t* __restrict__ zcat)
{
    const size_t e = ((size_t)blockIdx.x * 256 + threadIdx.x) * 8;
    const size_t tok = e >> 11;
    const int c = (int)(e & 2047);
    const float* src = (c < 1024) ? (zr + tok * 1024 + c) : (zi + tok * 1024 + (c - 1024));
    float4 a = *(const float4*)src;
    float4 b = *(const float4*)(src + 4);
    ushort_t* d = zcat + e;
    d[0]=f2bf(a.x); d[1]=f2bf(a.y); d[2]=f2bf(a.z); d[3]=f2bf(a.w);
    d[4]=f2bf(b.x); d[5]=f2bf(b.y); d[6]=f2bf(b.z); d[7]=f2bf(b.w);
}

// Wstack[n][c]: n<1024: [wr[n] | -wi[n]] ; n>=1024: [wi[n-1024] | wr[n-1024]]
__global__ __launch_bounds__(256)
void wstack_kernel(const float* __restrict__ wr, const float* __restrict__ wi,
                   ushort_t* __restrict__ ws)
{
    const size_t e = ((size_t)blockIdx.x * 256 + threadIdx.x) * 8;
    const int n = (int)(e >> 11), c = (int)(e & 2047);
    const int n1 = n & 1023, c1 = c & 1023;
    const float* src;
    float sgn = 1.f;
    if (n < 1024) {
        if (c < 1024) src = wr + (size_t)n1 * 1024 + c1;
        else        { src = wi + (size_t)n1 * 1024 + c1; sgn = -1.f; }
    } else {
        src = ((c < 1024) ? wi : wr) + (size_t)n1 * 1024 + c1;
    }
    float4 a = *(const float4*)src;
    float4 b = *(const float4*)(src + 4);
    ushort_t* d = ws + e;
    d[0]=f2bf(sgn*a.x); d[1]=f2bf(sgn*a.y); d[2]=f2bf(sgn*a.z); d[3]=f2bf(sgn*a.w);
    d[4]=f2bf(sgn*b.x); d[5]=f2bf(sgn*b.y); d[6]=f2bf(sgn*b.z); d[7]=f2bf(sgn*b.w);
}

// ---------------------------------------------------------------------------
// V transpose per batch: VT[b][c][t] = Vcat[b*SEQ + t][c], 64x64 LDS tiles.
// grid (32 t-tiles, 32 c-tiles, 4 batches)
// ---------------------------------------------------------------------------
__global__ __launch_bounds__(256)
void transpose_v(const ushort_t* __restrict__ vcat, ushort_t* __restrict__ vt)
{
    __shared__ ushort_t tile[64][65];
    const int b = blockIdx.z;
    const int t0 = blockIdx.x * 64, c0 = blockIdx.y * 64;
    const int tid = threadIdx.x;
    const int r = tid >> 4, c4 = (tid & 15) * 4;
    const ushort_t* src = vcat + ((size_t)(b * SEQ + t0)) * LD + c0;
    #pragma unroll
    for (int p = 0; p < 4; ++p) {
        const int row = p * 16 + r;
        ushort4 v = *(const ushort4*)(src + (size_t)row * LD + c4);
        tile[row][c4+0]=v.x; tile[row][c4+1]=v.y; tile[row][c4+2]=v.z; tile[row][c4+3]=v.w;
    }
    __syncthreads();
    ushort_t* dst = vt + ((size_t)b * LD + c0) * LD + t0;
    #pragma unroll
    for (int p = 0; p < 4; ++p) {
        const int crow = p * 16 + r;
        ushort4 v;
        v.x = tile[c4+0][crow]; v.y = tile[c4+1][crow];
        v.z = tile[c4+2][crow]; v.w = tile[c4+3][crow];
        *(ushort4*)(dst + (size_t)crow * LD + c4) = v;
    }
}

// ---------------------------------------------------------------------------
// Causal softmax: read fp16 scores row [0,s], write bf16 P in place,
// zero-padded to a 256 multiple so the 256-tile PV consumes whole K tiles.
// ---------------------------------------------------------------------------
__global__ __launch_bounds__(256)
void softmax_kernel(__half* __restrict__ sc)
{
    const int row = blockIdx.x;          // b*SEQ + s
    const int s = row & (SEQ - 1);
    __half* x = sc + (size_t)row * SEQ;
    ushort_t* xo = (ushort_t*)x;
    const int n = s + 1;
    const int tid = threadIdx.x, wave = tid >> 6, lane = tid & 63;
    __shared__ float redm[4], reds[4];

    float m = -1e30f;
    for (int i = tid; i < n; i += 256) m = fmaxf(m, __half2float(x[i]));
    #pragma unroll
    for (int off = 32; off > 0; off >>= 1) m = fmaxf(m, __shfl_down(m, off, 64));
    if (lane == 0) redm[wave] = m;
    __syncthreads();
    if (tid == 0) redm[0] = fmaxf(fmaxf(redm[0], redm[1]), fmaxf(redm[2], redm[3]));
    __syncthreads();
    m = redm[0];

    float l = 0.f;
    for (int i = tid; i < n; i += 256) l += __expf(__half2float(x[i]) - m);
    #pragma unroll
    for (int off = 32; off > 0; off >>= 1) l += __shfl_down(l, off, 64);
    if (lane == 0) reds[wave] = l;
    __syncthreads();
    if (tid == 0) reds[0] = reds[0] + reds[1] + reds[2] + reds[3];
    __syncthreads();
    const float inv = 1.0f / reds[0];

    const int npad = min(SEQ, ((s >> 8) + 1) << 8);   // pad to 256 for PV tiles
    for (int i = tid; i < npad; i += 256) {
        float v = (i < n) ? __expf(__half2float(x[i]) - m) * inv : 0.f;
        xo[i] = f2bf(v);
    }
}

// ---------------------------------------------------------------------------
extern "C" void kernel_launch(void* const* d_in, const int* in_sizes, int n_in,
                              void* d_out, int out_size, void* d_ws, size_t ws_size,
                              hipStream_t stream)
{
    const float* z_real = (const float*)d_in[0];
    const float* z_imag = (const float*)d_in[1];
    const float* wq_r   = (const float*)d_in[2];
    const float* wq_i   = (const float*)d_in[3];
    const float* wk_r   = (const float*)d_in[4];
    const float* wk_i   = (const float*)d_in[5];
    const float* wv_r   = (const float*)d_in[6];
    const float* wv_i   = (const float*)d_in[7];
    // d_in[8]: causal tril mask, handled analytically.

    // Workspace layout (bytes), lifetimes are disjoint by stream order:
    //   [0,          33554432)  Zcat bf16     -> reused as VT bf16
    //   [33554432,   58720256)  Wstack q/k/v bf16 (3 x 8 MiB, contiguous = Wall[6144,2048])
    //   [58720256,   92274688)  Qcat bf16
    //   [92274688,  125829120)  Kcat bf16
    //   [125829120, 159383552)  Vcat bf16     -> reused as scores fp16 / P bf16
    uint8_t* ws = (uint8_t*)d_ws;
    ushort_t* zcat = (ushort_t*)(ws + 0);
    ushort_t* wall = (ushort_t*)(ws + 33554432);
    ushort_t* wsq  = wall;
    ushort_t* wsk  = (ushort_t*)(ws + 33554432 + 8388608);
    ushort_t* wsv  = (ushort_t*)(ws + 33554432 + 16777216);
    ushort_t* qcat = (ushort_t*)(ws + 58720256);
    ushort_t* kcat = (ushort_t*)(ws + 92274688);
    ushort_t* vcat = (ushort_t*)(ws + 125829120);
    ushort_t* vt   = (ushort_t*)(ws + 0);
    __half*   sc   = (__half*)(ws + 125829120);
    float*    outp = (float*)d_out;

    zcat_kernel<<<dim3(8192), dim3(256), 0, stream>>>(z_real, z_imag, zcat);
    wstack_kernel<<<dim3(2048), dim3(256), 0, stream>>>(wq_r, wq_i, wsq);
    wstack_kernel<<<dim3(2048), dim3(256), 0, stream>>>(wk_r, wk_i, wsk);
    wstack_kernel<<<dim3(2048), dim3(256), 0, stream>>>(wv_r, wv_i, wsv);

    gemm_proj<<<dim3(24, 32), dim3(512), 0, stream>>>(zcat, wall, qcat, kcat, vcat);

    transpose_v<<<dim3(32, 32, 4), dim3(256), 0, stream>>>(vcat, vt);
    gemm_scores<<<dim3(8, 8, 4), dim3(512), 0, stream>>>(qcat, kcat, sc);
    softmax_kernel<<<dim3(NTOK), dim3(256), 0, stream>>>(sc);
    gemm_pv<<<dim3(8, 8, 4), dim3(512), 0, stream>>>((ushort_t*)sc, vt, outp);
}